// Round 1
// baseline (2039.797 us; speedup 1.0000x reference)
//
#include <hip/hip_runtime.h>

#define A3 180
#define A2 128
#define W2D 384
#define NV 192
#define NU 256
#define VZ 192
#define VY 192
#define VX 192
#define ZPT 8

static constexpr double PI_D = 3.14159265358979323846;

// ---------------- Kernel T: trig tables ----------------
__global__ void tables_kernel(float* __restrict__ c2, float* __restrict__ s2,
                              float* __restrict__ cbt, float* __restrict__ sbt) {
    int i = threadIdx.x;
    if (i < A2) {
        float th = (float)i * (float)(PI_D / A2);
        c2[i] = cosf(th);
        s2[i] = sinf(th);
    }
    if (i < A3) {
        float be = (float)i * (float)(2.0 * PI_D / A3);
        cbt[i] = cosf(be);
        sbt[i] = sinf(be);
    }
}

// ---------------- Kernel A: d = grad_last(sino * weight) ----------------
// One block per (a3,a2) row of W2D=384 elements.
__global__ __launch_bounds__(W2D) void grad_kernel(const float* __restrict__ sino,
                                                   const float* __restrict__ wini,
                                                   float* __restrict__ d) {
    __shared__ float p[W2D];
    size_t base = (size_t)blockIdx.x * W2D;
    int w = threadIdx.x;
    p[w] = sino[base + w] * wini[base + w];
    __syncthreads();
    float g;
    if (w == 0)            g = p[1] - p[0];
    else if (w == W2D - 1) g = p[W2D - 1] - p[W2D - 2];
    else                   g = (p[w + 1] - p[w - 1]) * 0.5f;
    d[base + w] = g;
}

// ---------------- Kernel B: 2D parallel BP + cosine weight ----------------
// thread = u, blockIdx.x = v, blockIdx.y = a3
__global__ __launch_bounds__(NU) void bp2d_kernel(const float* __restrict__ d,
                                                  const float* __restrict__ c2,
                                                  const float* __restrict__ s2,
                                                  float* __restrict__ wcb) {
    int u = threadIdx.x;
    int v = blockIdx.x;
    int a3 = blockIdx.y;
    float x = ((float)u - (NU - 1) * 0.5f) * 2.0f;  // DU = 2
    float y = ((float)v - (NV - 1) * 0.5f) * 2.0f;  // DV = 2
    const float* slab = d + (size_t)a3 * (A2 * W2D);
    float acc = 0.0f;
    for (int a = 0; a < A2; ++a) {
        float c = c2[a], s = s2[a];
        float pos = (x * c + y * s) * 0.5f + (W2D - 1) * 0.5f;  // /DS2D=2
        float fi = floorf(pos);
        int i0 = (int)fi;
        float f = pos - fi;
        int i1 = i0 + 1;
        float w0 = (1.0f - f) * ((i0 >= 0 && i0 < W2D) ? 1.0f : 0.0f);
        float w1 = f * ((i1 >= 0 && i1 < W2D) ? 1.0f : 0.0f);
        int i0c = min(max(i0, 0), W2D - 1);
        int i1c = min(max(i1, 0), W2D - 1);
        const float* row = slab + a * W2D;
        acc += row[i0c] * w0 + row[i1c] * w1;
    }
    // fuse: * (pi/A2) * DSD/sqrt(DSD^2 + us^2 + vs^2), us==x, vs==y
    float w3 = 1200.0f / sqrtf(1200.0f * 1200.0f + x * x + y * y);
    wcb[((size_t)a3 * NV + v) * NU + u] = acc * (float)(PI_D / A2) * w3;
}

// ---------------- Kernel C: cone-beam BP ----------------
// thread = x, blockIdx.x = y, blockIdx.y = z-group (ZPT z per thread)
__global__ __launch_bounds__(VX) void conebp_kernel(const float* __restrict__ wcb,
                                                    const float* __restrict__ cbt,
                                                    const float* __restrict__ sbt,
                                                    float* __restrict__ out) {
    int x = threadIdx.x;
    int y = blockIdx.x;
    int z0 = blockIdx.y * ZPT;
    float xf = (float)x - (VX - 1) * 0.5f;
    float yf = (float)y - (VY - 1) * 0.5f;
    float z0f = (float)z0 - (VZ - 1) * 0.5f;

    float acc[ZPT];
#pragma unroll
    for (int k = 0; k < ZPT; ++k) acc[k] = 0.0f;

    for (int a = 0; a < A3; ++a) {
        float cb = cbt[a], sb = sbt[a];
        float r = xf * cb + yf * sb;
        float t = -xf * sb + yf * cb;
        float denom = 750.0f - r;                 // DSO - r, never 0
        float inv = __builtin_amdgcn_rcpf(denom); // ~1 ulp, plenty for 2% thr
        float iu = 600.0f * t * inv + (NU - 1) * 0.5f;  // DSD*t/denom/DU
        float fiu = floorf(iu);
        int u0 = (int)fiu;
        float fu = iu - fiu;
        int u1 = u0 + 1;
        float m0u = (u0 >= 0 && u0 < NU) ? 1.0f : 0.0f;
        float m1u = (u1 >= 0 && u1 < NU) ? 1.0f : 0.0f;
        int u0c = min(max(u0, 0), NU - 1);
        int u1c = min(max(u1, 0), NU - 1);
        float w = 750.0f * inv;
        w = w * w;                                // (DSO/denom)^2
        float wa = (1.0f - fu) * m0u * w;
        float wb = fu * m1u * w;
        float dstep = 600.0f * inv;               // DSD/denom/DV per unit z
        float iv0 = dstep * z0f + (NV - 1) * 0.5f;
        const float* slab = wcb + (size_t)a * (NV * NU);
#pragma unroll
        for (int k = 0; k < ZPT; ++k) {
            float iv = iv0 + (float)k * dstep;
            float fiv = floorf(iv);
            int v0 = (int)fiv;
            float fv = iv - fiv;
            int v1 = v0 + 1;
            float m0v = (v0 >= 0 && v0 < NV) ? 1.0f : 0.0f;
            float m1v = (v1 >= 0 && v1 < NV) ? 1.0f : 0.0f;
            int v0c = min(max(v0, 0), NV - 1);
            int v1c = min(max(v1, 0), NV - 1);
            int o0 = v0c * NU;
            int o1 = v1c * NU;
            float p00 = slab[o0 + u0c];
            float p01 = slab[o0 + u1c];
            float p10 = slab[o1 + u0c];
            float p11 = slab[o1 + u1c];
            float row0 = p00 * wa + p01 * wb;
            float row1 = p10 * wa + p11 * wb;
            acc[k] += (1.0f - fv) * m0v * row0 + fv * m1v * row1;
        }
    }
    float scale = (float)(2.0 * PI_D / A3);
#pragma unroll
    for (int k = 0; k < ZPT; ++k) {
        out[(((size_t)(z0 + k)) * VY + y) * VX + x] = acc[k] * scale;
    }
}

extern "C" void kernel_launch(void* const* d_in, const int* in_sizes, int n_in,
                              void* d_out, int out_size, void* d_ws, size_t ws_size,
                              hipStream_t stream) {
    const float* sino = (const float*)d_in[0];  // [1,1,A3,A2,W2D] flat
    const float* wini = (const float*)d_in[1];  // [A3,A2,W2D] flat
    float* out = (float*)d_out;                 // [1,VZ,VY,VX] flat

    // workspace layout (needs ~70.9 MB)
    float* d   = (float*)d_ws;                        // A3*A2*W2D
    float* wcb = d + (size_t)A3 * A2 * W2D;           // A3*NV*NU
    float* c2  = wcb + (size_t)A3 * NV * NU;
    float* s2  = c2 + A2;
    float* cbt = s2 + A2;
    float* sbt = cbt + A3;

    tables_kernel<<<1, 256, 0, stream>>>(c2, s2, cbt, sbt);
    grad_kernel<<<A3 * A2, W2D, 0, stream>>>(sino, wini, d);
    bp2d_kernel<<<dim3(NV, A3), NU, 0, stream>>>(d, c2, s2, wcb);
    conebp_kernel<<<dim3(VY, VZ / ZPT), VX, 0, stream>>>(wcb, cbt, sbt, out);
}

// Round 2
// 1943.774 us; speedup vs baseline: 1.0494x; 1.0494x over previous
//
#include <hip/hip_runtime.h>

#define A3 180
#define A2 128
#define W2D 384
#define NV 192
#define NU 256
#define VZ 192
#define VY 192
#define VX 192
#define ZPT 16

static constexpr double PI_D = 3.14159265358979323846;

// ---------------- Kernel T: trig tables ----------------
__global__ void tables_kernel(float* __restrict__ c2, float* __restrict__ s2,
                              float* __restrict__ cbt, float* __restrict__ sbt) {
    int i = threadIdx.x;
    if (i < A2) {
        float th = (float)i * (float)(PI_D / A2);
        c2[i] = cosf(th);
        s2[i] = sinf(th);
    }
    if (i < A3) {
        float be = (float)i * (float)(2.0 * PI_D / A3);
        cbt[i] = cosf(be);
        sbt[i] = sinf(be);
    }
}

// ---------------- Kernel A: d = grad_last(sino * weight) ----------------
__global__ __launch_bounds__(W2D) void grad_kernel(const float* __restrict__ sino,
                                                   const float* __restrict__ wini,
                                                   float* __restrict__ d) {
    __shared__ float p[W2D];
    size_t base = (size_t)blockIdx.x * W2D;
    int w = threadIdx.x;
    p[w] = sino[base + w] * wini[base + w];
    __syncthreads();
    float g;
    if (w == 0)            g = p[1] - p[0];
    else if (w == W2D - 1) g = p[W2D - 1] - p[W2D - 2];
    else                   g = (p[w + 1] - p[w - 1]) * 0.5f;
    d[base + w] = g;
}

// ---------------- Kernel B: 2D parallel BP + cosine weight ----------------
// pos = (x*c + y*s)/2 + 191.5 is provably in [32.2, 350.8] -> no masks, no
// clamps, trunc==floor, i1 = i0+1 always (offset:4 fold).
// Fused output scale: (pi/A2) * w3 * (2*pi/A3)  [cone-BP scale folded in].
__global__ __launch_bounds__(NU) void bp2d_kernel(const float* __restrict__ d,
                                                  const float* __restrict__ c2,
                                                  const float* __restrict__ s2,
                                                  float* __restrict__ wcb) {
    int u = threadIdx.x;
    int v = blockIdx.x;
    int a3 = blockIdx.y;
    float x = ((float)u - 127.5f) * 2.0f;
    float y = ((float)v - 95.5f) * 2.0f;
    const float* slab = d + (size_t)a3 * (A2 * W2D);
    float acc = 0.0f;
    for (int a = 0; a < A2; ++a) {
        float c = c2[a], s = s2[a];
        float pos = (x * c + y * s) * 0.5f + 191.5f;
        int i0 = (int)pos;              // pos > 0 -> trunc == floor
        float f = pos - (float)i0;
        const float* row = slab + a * W2D;
        float r0 = row[i0];
        float r1 = row[i0 + 1];
        acc += r0 + f * (r1 - r0);
    }
    float w3 = 1200.0f * __builtin_amdgcn_rsqf(1440000.0f + x * x + y * y);
    float scale = (float)((PI_D / A2) * (2.0 * PI_D / A3));
    wcb[((size_t)a3 * NV + v) * NU + u] = acc * scale * w3;
}

// ---------------- Kernel C: cone-beam BP ----------------
// iv = 600*zf*inv + 95.5 is provably in [2.32, 188.68] -> v always in-bounds,
// v1 = v0+1 (row +1024B fold), trunc==floor. u-masks folded into wa/wb with
// the (DSO/denom)^2 weight, hoisted per-beta. Output scale folded into wcb.
__global__ __launch_bounds__(VX) void conebp_kernel(const float* __restrict__ wcb,
                                                    const float* __restrict__ cbt,
                                                    const float* __restrict__ sbt,
                                                    float* __restrict__ out) {
    int x = threadIdx.x;
    int y = blockIdx.x;
    int z0 = blockIdx.y * ZPT;
    float xf = (float)x - 95.5f;
    float yf = (float)y - 95.5f;
    float z0f = (float)z0 - 95.5f;

    float acc[ZPT];
#pragma unroll
    for (int k = 0; k < ZPT; ++k) acc[k] = 0.0f;

    for (int a = 0; a < A3; ++a) {
        float cb = cbt[a], sb = sbt[a];
        float r = xf * cb + yf * sb;
        float t = yf * cb - xf * sb;
        float inv = __builtin_amdgcn_rcpf(750.0f - r);
        float iu = 600.0f * t * inv + 127.5f;
        float fiu = floorf(iu);          // iu can be negative -> need floor
        int u0 = (int)fiu;
        float fu = iu - fiu;
        int u0c = min(max(u0, 0), NU - 1);
        int u1c = min(max(u0 + 1, 0), NU - 1);
        float w = 750.0f * inv;
        w = w * w;                        // (DSO/denom)^2
        float wa = (u0 >= 0 && u0 < NU) ? (1.0f - fu) * w : 0.0f;
        float wb = (u0 >= -1 && u0 < NU - 1) ? fu * w : 0.0f;
        float dstep = 600.0f * inv;       // d(iv)/dz
        float iv0 = dstep * z0f + 95.5f;
        const float* slab = wcb + (size_t)a * (NV * NU);
        const float* col0 = slab + u0c;
        const float* col1 = slab + u1c;
#pragma unroll
        for (int k = 0; k < ZPT; ++k) {
            float iv = iv0 + (float)k * dstep;
            int v0 = (int)iv;             // iv in [2.3,188.7] -> trunc==floor
            float fv = iv - (float)v0;
            int o = v0 << 8;              // v0 * NU
            float p00 = col0[o];
            float p01 = col1[o];
            float p10 = col0[o + NU];     // v1 = v0+1 always: +1024B imm
            float p11 = col1[o + NU];
            float r0 = p00 * wa + p01 * wb;
            float r1 = p10 * wa + p11 * wb;
            acc[k] += r0 + fv * (r1 - r0);
        }
    }
#pragma unroll
    for (int k = 0; k < ZPT; ++k) {
        out[(((size_t)(z0 + k)) * VY + y) * VX + x] = acc[k];
    }
}

extern "C" void kernel_launch(void* const* d_in, const int* in_sizes, int n_in,
                              void* d_out, int out_size, void* d_ws, size_t ws_size,
                              hipStream_t stream) {
    const float* sino = (const float*)d_in[0];  // [1,1,A3,A2,W2D] flat
    const float* wini = (const float*)d_in[1];  // [A3,A2,W2D] flat
    float* out = (float*)d_out;                 // [1,VZ,VY,VX] flat

    float* d   = (float*)d_ws;                        // A3*A2*W2D
    float* wcb = d + (size_t)A3 * A2 * W2D;           // A3*NV*NU
    float* c2  = wcb + (size_t)A3 * NV * NU;
    float* s2  = c2 + A2;
    float* cbt = s2 + A2;
    float* sbt = cbt + A3;

    tables_kernel<<<1, 256, 0, stream>>>(c2, s2, cbt, sbt);
    grad_kernel<<<A3 * A2, W2D, 0, stream>>>(sino, wini, d);
    bp2d_kernel<<<dim3(NV, A3), NU, 0, stream>>>(d, c2, s2, wcb);
    conebp_kernel<<<dim3(VY, VZ / ZPT), VX, 0, stream>>>(wcb, cbt, sbt, out);
}

// Round 3
// 1807.482 us; speedup vs baseline: 1.1285x; 1.0754x over previous
//
#include <hip/hip_runtime.h>

#define A3 180
#define A2 128
#define W2D 384
#define NV 192
#define NU 256
#define VZ 192
#define VY 192
#define VX 192
#define ZPT 16
#define ACHUNK 8

static constexpr double PI_D = 3.14159265358979323846;

// ---------------- Kernel T: trig tables ----------------
__global__ void tables_kernel(float* __restrict__ c2, float* __restrict__ s2,
                              float* __restrict__ cbt, float* __restrict__ sbt) {
    int i = threadIdx.x;
    if (i < A2) {
        float th = (float)i * (float)(PI_D / A2);
        c2[i] = cosf(th);
        s2[i] = sinf(th);
    }
    if (i < A3) {
        float be = (float)i * (float)(2.0 * PI_D / A3);
        cbt[i] = cosf(be);
        sbt[i] = sinf(be);
    }
}

// ---------------- Kernel A: d = grad_last(sino * weight) ----------------
__global__ __launch_bounds__(W2D) void grad_kernel(const float* __restrict__ sino,
                                                   const float* __restrict__ wini,
                                                   float* __restrict__ d) {
    __shared__ float p[W2D];
    size_t base = (size_t)blockIdx.x * W2D;
    int w = threadIdx.x;
    p[w] = sino[base + w] * wini[base + w];
    __syncthreads();
    float g;
    if (w == 0)            g = p[1] - p[0];
    else if (w == W2D - 1) g = p[W2D - 1] - p[W2D - 2];
    else                   g = (p[w + 1] - p[w - 1]) * 0.5f;
    d[base + w] = g;
}

// ---------------- Kernel B: 2D parallel BP + cosine weight ----------------
// pos = uf*c + (vf*s + 191.5) provably in [32.2, 350.8]: no masks, trunc==floor.
// Chunked phase-split (8 angles of loads in flight, then FMAs).
__global__ __launch_bounds__(NU) void bp2d_kernel(const float* __restrict__ d,
                                                  const float* __restrict__ c2,
                                                  const float* __restrict__ s2,
                                                  float* __restrict__ wcb) {
    int u = threadIdx.x;
    int v = blockIdx.x;
    int a3 = blockIdx.y;
    float uf = (float)u - 127.5f;           // x/2
    float vf = (float)v - 95.5f;            // y/2
    unsigned slab = (unsigned)a3 * (A2 * W2D);
    float acc = 0.0f;
    for (int a0 = 0; a0 < A2; a0 += ACHUNK) {
        float r0v[ACHUNK], r1v[ACHUNK], fv[ACHUNK];
#pragma unroll
        for (int j = 0; j < ACHUNK; ++j) {
            int a = a0 + j;
            float pos = fmaf(uf, c2[a], fmaf(vf, s2[a], 191.5f));
            int i0 = (int)pos;              // pos > 0 -> trunc == floor
            fv[j] = pos - (float)i0;
            unsigned off = slab + (unsigned)(a * W2D) + (unsigned)i0;
            r0v[j] = d[off];
            r1v[j] = d[off + 1];
        }
        __builtin_amdgcn_sched_barrier(0);
#pragma unroll
        for (int j = 0; j < ACHUNK; ++j) {
            acc += fmaf(fv[j], r1v[j] - r0v[j], r0v[j]);
        }
    }
    float x = uf * 2.0f, y = vf * 2.0f;
    float w3 = 1200.0f * __builtin_amdgcn_rsqf(1440000.0f + x * x + y * y);
    float scale = (float)((PI_D / A2) * (2.0 * PI_D / A3));
    wcb[((size_t)a3 * NV + v) * NU + u] = acc * scale * w3;
}

// ---------------- Kernel C: cone-beam BP ----------------
// Per beta: issue all 64 gathers (16 z x 4 taps) into registers, then FMA.
// sched_barrier(0) pins the load phase; SADDR-form loads via unsigned element
// offsets against the uniform wcb base (v+1 row = +256 elems -> offset imm).
__global__ __launch_bounds__(VX) void conebp_kernel(const float* __restrict__ wcb,
                                                    const float* __restrict__ cbt,
                                                    const float* __restrict__ sbt,
                                                    float* __restrict__ out) {
    int x = threadIdx.x;
    int y = blockIdx.x;
    int z0 = blockIdx.y * ZPT;
    float xf = (float)x - 95.5f;
    float yf = (float)y - 95.5f;
    float z0f = (float)z0 - 95.5f;

    float acc[ZPT];
#pragma unroll
    for (int k = 0; k < ZPT; ++k) acc[k] = 0.0f;

    for (int a = 0; a < A3; ++a) {
        float cb = cbt[a], sb = sbt[a];
        float r = xf * cb + yf * sb;
        float t = yf * cb - xf * sb;
        float inv = __builtin_amdgcn_rcpf(750.0f - r);
        float iu = 600.0f * t * inv + 135.5f;   // 127.5 + 8 bias -> iu > 0
        int u0b = (int)iu;                       // trunc == floor
        float fu = iu - (float)u0b;
        int u0 = u0b - 8;
        int u0c = min(max(u0, 0), NU - 1);
        int u1c = min(max(u0 + 1, 0), NU - 1);
        float w = 750.0f * inv;
        w = w * w;                               // (DSO/denom)^2
        float wa = (u0 >= 0 && u0 < NU) ? (1.0f - fu) * w : 0.0f;
        float wb = (u0 >= -1 && u0 < NU - 1) ? fu * w : 0.0f;
        float dstep = 600.0f * inv;
        float iv0 = dstep * z0f + 95.5f;         // iv in [2.3, 188.7] always
        unsigned abase = (unsigned)a * (NV * NU);
        unsigned sl0 = abase + (unsigned)u0c;
        unsigned sl1 = abase + (unsigned)u1c;

        float p00[ZPT], p01[ZPT], p10[ZPT], p11[ZPT], fvv[ZPT];
#pragma unroll
        for (int k = 0; k < ZPT; ++k) {
            float iv = iv0 + (float)k * dstep;
            int v0 = (int)iv;                    // trunc == floor
            fvv[k] = iv - (float)v0;
            unsigned o = ((unsigned)v0) << 8;    // v0 * NU
            p00[k] = wcb[sl0 + o];
            p01[k] = wcb[sl1 + o];
            p10[k] = wcb[sl0 + o + NU];          // v1 = v0+1: +1024B imm
            p11[k] = wcb[sl1 + o + NU];
        }
        __builtin_amdgcn_sched_barrier(0);
#pragma unroll
        for (int k = 0; k < ZPT; ++k) {
            float r0 = fmaf(p00[k], wa, p01[k] * wb);
            float r1 = fmaf(p10[k], wa, p11[k] * wb);
            acc[k] = fmaf(fvv[k], r1 - r0, acc[k] + r0);
        }
    }
#pragma unroll
    for (int k = 0; k < ZPT; ++k) {
        out[(((size_t)(z0 + k)) * VY + y) * VX + x] = acc[k];
    }
}

extern "C" void kernel_launch(void* const* d_in, const int* in_sizes, int n_in,
                              void* d_out, int out_size, void* d_ws, size_t ws_size,
                              hipStream_t stream) {
    const float* sino = (const float*)d_in[0];  // [1,1,A3,A2,W2D] flat
    const float* wini = (const float*)d_in[1];  // [A3,A2,W2D] flat
    float* out = (float*)d_out;                 // [1,VZ,VY,VX] flat

    float* d   = (float*)d_ws;                        // A3*A2*W2D
    float* wcb = d + (size_t)A3 * A2 * W2D;           // A3*NV*NU
    float* c2  = wcb + (size_t)A3 * NV * NU;
    float* s2  = c2 + A2;
    float* cbt = s2 + A2;
    float* sbt = cbt + A3;

    tables_kernel<<<1, 256, 0, stream>>>(c2, s2, cbt, sbt);
    grad_kernel<<<A3 * A2, W2D, 0, stream>>>(sino, wini, d);
    bp2d_kernel<<<dim3(NV, A3), NU, 0, stream>>>(d, c2, s2, wcb);
    conebp_kernel<<<dim3(VY, VZ / ZPT), VX, 0, stream>>>(wcb, cbt, sbt, out);
}